// Round 2
// baseline (9962.691 us; speedup 1.0000x reference)
//
#include <hip/hip_runtime.h>

#define T_LEN 8192
#define HH 128
#define G4 512
#define E_DIM 50
#define KT 23
#define START_T 21
#define STOP_T 22
#define NEGV -10000.0f

__device__ __forceinline__ float rl(float v, int lane) {
  return __int_as_float(__builtin_amdgcn_readlane(__float_as_int(v), lane));
}

// ---------------------------------------------------------------------------
// K1: pre[t][j] = Wih[row(j)] . x_t + bih + bhh   (row permuted for k_lstm)
// row(j) = ((j&3)<<7) | (j>>2)  -> lane quads hold i,f,g,o of one hidden dim
// ---------------------------------------------------------------------------
__global__ __launch_bounds__(512) void k_pre(
    const int* __restrict__ sentence, const float* __restrict__ embed,
    const float* __restrict__ Wih_f, const float* __restrict__ bih_f, const float* __restrict__ bhh_f,
    const float* __restrict__ Wih_b, const float* __restrict__ bih_b, const float* __restrict__ bhh_b,
    float* __restrict__ pre_f, float* __restrict__ pre_b)
{
  const int dir = blockIdx.x >> 8;
  const int t0 = (blockIdx.x & 255) * 32;
  const float* __restrict__ Wih = dir ? Wih_b : Wih_f;
  const float* __restrict__ bi  = dir ? bih_b : bih_f;
  const float* __restrict__ bh  = dir ? bhh_b : bhh_f;
  float* __restrict__ pre = dir ? pre_b : pre_f;
  const int j = threadIdx.x;
  const int r = ((j & 3) << 7) | (j >> 2);
  float w[E_DIM];
  {
    const float2* w2 = (const float2*)(Wih + r * E_DIM);
#pragma unroll
    for (int q = 0; q < 25; ++q) { float2 v = w2[q]; w[2*q] = v.x; w[2*q+1] = v.y; }
  }
  const float bias = bi[r] + bh[r];
  __shared__ float xs[32][E_DIM];
  __shared__ int sidx[32];
  if (j < 32) sidx[j] = sentence[t0 + j];
  __syncthreads();
  for (int i = j; i < 32 * E_DIM; i += 512) {
    int tl = i / E_DIM;
    int e = i - tl * E_DIM;
    xs[tl][e] = embed[sidx[tl] * E_DIM + e];
  }
  __syncthreads();
  for (int tl = 0; tl < 32; ++tl) {
    float a0 = bias, a1 = 0.f;
#pragma unroll
    for (int e = 0; e < E_DIM; e += 2) {
      a0 += w[e]     * xs[tl][e];
      a1 += w[e + 1] * xs[tl][e + 1];
    }
    pre[(t0 + tl) * G4 + j] = a0 + a1;
  }
}

// ---------------------------------------------------------------------------
// K2: serial LSTM, 1 CU per direction. Thread j owns Whh row ((j&3)<<7)|(j>>2)
// in 128 VGPRs. Dot chunked 4x(8 ds_read_b128 + 32 fma) with sched_barrier(0)
// between chunks: caps live h-regs at 32 so w[] stays in arch VGPRs (R1 showed
// VGPR_Count=80 + AGPR copies when the scheduler hoisted all 32 LDS reads).
// ---------------------------------------------------------------------------
__global__ __launch_bounds__(512, 2) void k_lstm(
    const float* __restrict__ Whh_f, const float* __restrict__ Whh_b,
    const float* __restrict__ h0, const float* __restrict__ c0,
    const float* __restrict__ pre_f, const float* __restrict__ pre_b,
    float* __restrict__ hcat)
{
  const int dir = blockIdx.x;
  const float* __restrict__ Whh = dir ? Whh_b : Whh_f;
  const float* __restrict__ pre = dir ? pre_b : pre_f;
  const int j = threadIdx.x;
  const int g = j & 3;        // 0=i,1=f,2=g,3=o
  const int d = j >> 2;       // hidden dim
  const int r = (g << 7) | d; // Whh row
  float w[128];
  {
    const float4* w4 = (const float4*)(Whh + r * 128);
#pragma unroll
    for (int q = 0; q < 32; ++q) {
      float4 v = w4[q];
      w[4*q+0] = v.x; w[4*q+1] = v.y; w[4*q+2] = v.z; w[4*q+3] = v.w;
    }
  }
  __shared__ float hbuf[2][HH];
  float c = c0[dir * HH + d];
  if (g == 0) hbuf[0][d] = h0[dir * HH + d];
  __syncthreads();
  float pcur = pre[(dir ? (T_LEN - 1) : 0) * G4 + j];
  for (int s = 0; s < T_LEN; ++s) {
    const int t = dir ? (T_LEN - 1 - s) : s;
    const int sn = (s + 1 < T_LEN) ? (s + 1) : s;
    const int tn = dir ? (T_LEN - 1 - sn) : sn;
    const float pnext = pre[tn * G4 + j];   // prefetch 1 step ahead
    const float4* h4 = (const float4*)hbuf[s & 1];
    float a0 = 0.f, a1 = 0.f, a2 = 0.f, a3 = 0.f;
#pragma unroll
    for (int ch = 0; ch < 4; ++ch) {
#pragma unroll
      for (int q = ch * 8; q < ch * 8 + 8; ++q) {
        float4 hv = h4[q];
        a0 += w[4*q+0] * hv.x;
        a1 += w[4*q+1] * hv.y;
        a2 += w[4*q+2] * hv.z;
        a3 += w[4*q+3] * hv.w;
      }
      __builtin_amdgcn_sched_barrier(0);   // cap live h-regs -> keep w in VGPRs
    }
    const float acc = ((a0 + a1) + (a2 + a3)) + pcur;
    pcur = pnext;
    const float sc = (g == 2) ? 2.0f : 1.0f;
    const float ev = __expf(-sc * acc);
    const float sg = 1.0f / (1.0f + ev);
    const float act = (g == 2) ? (2.0f * sg - 1.0f) : sg;
    const float iv  = __shfl(act, 0, 4);
    const float fv  = __shfl(act, 1, 4);
    const float gv  = __shfl(act, 2, 4);
    const float ovv = __shfl(act, 3, 4);
    c = fv * c + iv * gv;
    const float e2 = __expf(-2.0f * c);
    const float th = 2.0f / (1.0f + e2) - 1.0f;
    const float h = ovv * th;
    if (g == 0) {
      hbuf[(s + 1) & 1][d] = h;            // double-buffer: 1 barrier/step
      hcat[t * (2 * HH) + dir * HH + d] = h;
    }
    __syncthreads();
  }
}

// ---------------------------------------------------------------------------
// K3: feats[t][k] = W_out[k] . hcat[t] + b_out[k]
// ---------------------------------------------------------------------------
__global__ __launch_bounds__(256) void k_feats(
    const float* __restrict__ hcat, const float* __restrict__ Wout,
    const float* __restrict__ bout, float* __restrict__ feats)
{
  const int t0 = blockIdx.x * 32;
  __shared__ float hsh[32 * 257];
  __shared__ float wsh[KT * 256];
  __shared__ float bsh[KT];
  const int tid = threadIdx.x;
  for (int i = tid; i < 32 * 256; i += 256) {
    int tl = i >> 8, dd = i & 255;
    hsh[tl * 257 + dd] = hcat[(t0 + tl) * 256 + dd];
  }
  for (int i = tid; i < KT * 256; i += 256) wsh[i] = Wout[i];
  if (tid < KT) bsh[tid] = bout[tid];
  __syncthreads();
  for (int idx = tid; idx < 32 * KT; idx += 256) {
    int tl = idx & 31, k = idx >> 5;
    float a0 = bsh[k], a1 = 0.f, a2 = 0.f, a3 = 0.f;
#pragma unroll 8
    for (int dd = 0; dd < 256; dd += 4) {
      a0 += hsh[tl * 257 + dd + 0] * wsh[k * 256 + dd + 0];
      a1 += hsh[tl * 257 + dd + 1] * wsh[k * 256 + dd + 1];
      a2 += hsh[tl * 257 + dd + 2] * wsh[k * 256 + dd + 2];
      a3 += hsh[tl * 257 + dd + 3] * wsh[k * 256 + dd + 3];
    }
    feats[(t0 + tl) * KT + k] = ((a0 + a1) + (a2 + a3));
  }
}

// ---------------------------------------------------------------------------
// K4: sequential Viterbi forward, 1 wave, lane j = next-tag.
// Serial chain = readlane-bcast + add + max3-tree(depth 3) + add feat only.
// Argmax index (bptr) is computed ONE STEP DEFERRED (equality vs exact max +
// min3_u32 tree = first-max, identical to jnp.argmax) so it overlaps the
// next step's dependent phase. fv values bitwise identical to R1.
// ---------------------------------------------------------------------------
__global__ __launch_bounds__(64) void k_vit_fwd(
    const float* __restrict__ feats, const float* __restrict__ trans,
    unsigned char* __restrict__ bptr, float* __restrict__ out, int* __restrict__ misc)
{
  const int j = threadIdx.x;
  float trow[KT];
#pragma unroll
  for (int i = 0; i < KT; ++i)
    trow[i] = (j < KT) ? ((j == START_T || i == STOP_T) ? NEGV : trans[j * KT + i]) : NEGV;
  float fvn = (j == START_T) ? 0.0f : NEGV;
  float pf[8];
#pragma unroll
  for (int q = 0; q < 8; ++q) pf[q] = (j < KT) ? feats[q * KT + j] : 0.0f;

  float candA[KT], candB[KT];
  float bestA = 0.0f, bestB = 0.0f;
#pragma unroll
  for (int i = 0; i < KT; ++i) { candA[i] = 0.0f; candB[i] = 0.0f; }

#define MAX3(a,b,cc) fmaxf(fmaxf((a),(b)),(cc))
#define MIN3(a,b,cc) min(min((a),(b)),(cc))

#define VSTEP(CUR, PREV, BCUR, BPREV, Q)                                       \
  {                                                                            \
    const int t = tb + (Q);                                                    \
    _Pragma("unroll")                                                          \
    for (int i = 0; i < KT; ++i) CUR[i] = rl(fvn, i) + trow[i];                \
    float m0 = MAX3(CUR[0], CUR[1], CUR[2]);                                   \
    float m1 = MAX3(CUR[3], CUR[4], CUR[5]);                                   \
    float m2 = MAX3(CUR[6], CUR[7], CUR[8]);                                   \
    float m3 = MAX3(CUR[9], CUR[10], CUR[11]);                                 \
    float m4 = MAX3(CUR[12], CUR[13], CUR[14]);                                \
    float m5 = MAX3(CUR[15], CUR[16], CUR[17]);                                \
    float m6 = MAX3(CUR[18], CUR[19], CUR[20]);                                \
    float m7 = fmaxf(CUR[21], CUR[22]);                                        \
    float n0 = MAX3(m0, m1, m2);                                               \
    float n1 = MAX3(m3, m4, m5);                                               \
    float n2 = fmaxf(m6, m7);                                                  \
    const float best = MAX3(n0, n1, n2);                                       \
    BCUR = best;                                                               \
    fvn = best + pf[Q];                                                        \
    const int tpf = t + 8;                                                     \
    pf[Q] = (j < KT && tpf < T_LEN) ? feats[tpf * KT + j] : 0.0f;              \
    /* deferred argmax for step t-1 (PREV/BPREV) — overlaps chain above */     \
    unsigned int ui[KT];                                                       \
    _Pragma("unroll")                                                          \
    for (int i = 0; i < KT; ++i) ui[i] = (PREV[i] == BPREV) ? (unsigned)i : 255u; \
    unsigned int p0 = MIN3(ui[0], ui[1], ui[2]);                               \
    unsigned int p1 = MIN3(ui[3], ui[4], ui[5]);                               \
    unsigned int p2 = MIN3(ui[6], ui[7], ui[8]);                               \
    unsigned int p3 = MIN3(ui[9], ui[10], ui[11]);                             \
    unsigned int p4 = MIN3(ui[12], ui[13], ui[14]);                            \
    unsigned int p5 = MIN3(ui[15], ui[16], ui[17]);                            \
    unsigned int p6 = MIN3(ui[18], ui[19], ui[20]);                            \
    unsigned int p7 = min(ui[21], ui[22]);                                     \
    unsigned int q0 = MIN3(p0, p1, p2);                                        \
    unsigned int q1 = MIN3(p3, p4, p5);                                        \
    unsigned int q2 = min(p6, p7);                                             \
    const unsigned int bi = MIN3(q0, q1, q2);                                  \
    const int pt = (t > 0) ? (t - 1) : 0;  /* t==0 garbage row, overwritten */ \
    if (j < KT) bptr[pt * KT + j] = (unsigned char)bi;                         \
  }

  for (int tb = 0; tb < T_LEN; tb += 8) {
    VSTEP(candA, candB, bestA, bestB, 0)
    VSTEP(candB, candA, bestB, bestA, 1)
    VSTEP(candA, candB, bestA, bestB, 2)
    VSTEP(candB, candA, bestB, bestA, 3)
    VSTEP(candA, candB, bestA, bestB, 4)
    VSTEP(candB, candA, bestB, bestA, 5)
    VSTEP(candA, candB, bestA, bestB, 6)
    VSTEP(candB, candA, bestB, bestA, 7)
  }
  // final step's (t = T-1, in candB/bestB) backpointers
  {
    unsigned int ui[KT];
#pragma unroll
    for (int i = 0; i < KT; ++i) ui[i] = (candB[i] == bestB) ? (unsigned)i : 255u;
    unsigned int p0 = MIN3(ui[0], ui[1], ui[2]);
    unsigned int p1 = MIN3(ui[3], ui[4], ui[5]);
    unsigned int p2 = MIN3(ui[6], ui[7], ui[8]);
    unsigned int p3 = MIN3(ui[9], ui[10], ui[11]);
    unsigned int p4 = MIN3(ui[12], ui[13], ui[14]);
    unsigned int p5 = MIN3(ui[15], ui[16], ui[17]);
    unsigned int p6 = MIN3(ui[18], ui[19], ui[20]);
    unsigned int p7 = min(ui[21], ui[22]);
    unsigned int q0 = MIN3(p0, p1, p2);
    unsigned int q1 = MIN3(p3, p4, p5);
    unsigned int q2 = min(p6, p7);
    const unsigned int bi = MIN3(q0, q1, q2);
    if (j < KT) bptr[(T_LEN - 1) * KT + j] = (unsigned char)bi;
  }
  // terminal: fv + trans_c[STOP]; first-max argmax via tie-aware butterfly
  const float trS = (j < KT) ? ((j == STOP_T) ? NEGV : trans[STOP_T * KT + j]) : 0.0f;
  float term = (j < KT) ? (fvn + trS) : -3.0e38f;
  int idx = (j < KT) ? j : 63;
#pragma unroll
  for (int off = 16; off >= 1; off >>= 1) {
    float ovl = __shfl_xor(term, off);
    int oi = __shfl_xor(idx, off);
    if (ovl > term || (ovl == term && oi < idx)) { term = ovl; idx = oi; }
  }
  if (j == 0) { out[0] = term; misc[0] = idx; }
}

// ---------------------------------------------------------------------------
// K5: compose 32-step backpointer maps per chunk (parallel).
// ---------------------------------------------------------------------------
__global__ __launch_bounds__(64) void k_compose(
    const unsigned char* __restrict__ bptr, unsigned char* __restrict__ maps)
{
  const int c = blockIdx.x;
  const int lo = c * 32;
  __shared__ unsigned char rows[32 * 24];
  const int tid = threadIdx.x;
  for (int i = tid; i < 32 * KT; i += 64) {
    int tl = i / KT, e = i - tl * KT;
    rows[tl * 24 + e] = bptr[(lo + tl) * KT + e];
  }
  __syncthreads();
  if (tid < KT) {
    int x = tid;
    for (int tl = 31; tl >= 0; --tl) x = rows[tl * 24 + x];
    maps[c * KT + tid] = (unsigned char)x;
  }
}

// K6: sequential scan over 256 chunk maps.
__global__ __launch_bounds__(64) void k_backscan(
    const unsigned char* __restrict__ maps, const int* __restrict__ misc,
    int* __restrict__ btags)
{
  __shared__ unsigned char msh[256 * KT];
  const int tid = threadIdx.x;
  for (int i = tid; i < 256 * KT; i += 64) msh[i] = maps[i];
  __syncthreads();
  if (tid == 0) {
    int e = misc[0];
    for (int c = 255; c >= 0; --c) { btags[c] = e; e = msh[c * KT + e]; }
  }
}

// K7: evaluate interior path per chunk (parallel), write tags as floats.
__global__ __launch_bounds__(64) void k_backeval(
    const unsigned char* __restrict__ bptr, const int* __restrict__ btags,
    float* __restrict__ out)
{
  const int c = blockIdx.x;
  const int lo = c * 32;
  __shared__ unsigned char rows[32 * 24];
  __shared__ int tags[32];
  const int tid = threadIdx.x;
  for (int i = tid; i < 32 * KT; i += 64) {
    int tl = i / KT, e = i - tl * KT;
    rows[tl * 24 + e] = bptr[(lo + tl) * KT + e];
  }
  __syncthreads();
  if (tid == 0) {
    int tg = btags[c];
    tags[31] = tg;
    for (int tl = 31; tl >= 1; --tl) { tg = rows[tl * 24 + tg]; tags[tl - 1] = tg; }
  }
  __syncthreads();
  if (tid < 32) out[1 + lo + tid] = (float)tags[tid];
}

// ---------------------------------------------------------------------------
extern "C" void kernel_launch(void* const* d_in, const int* in_sizes, int n_in,
                              void* d_out, int out_size, void* d_ws, size_t ws_size,
                              hipStream_t stream) {
  const int*   sentence = (const int*)d_in[0];
  const float* embed    = (const float*)d_in[1];
  const float* Wih_f    = (const float*)d_in[2];
  const float* Whh_f    = (const float*)d_in[3];
  const float* bih_f    = (const float*)d_in[4];
  const float* bhh_f    = (const float*)d_in[5];
  const float* Wih_b    = (const float*)d_in[6];
  const float* Whh_b    = (const float*)d_in[7];
  const float* bih_b    = (const float*)d_in[8];
  const float* bhh_b    = (const float*)d_in[9];
  const float* Wout     = (const float*)d_in[10];
  const float* bout     = (const float*)d_in[11];
  const float* trans    = (const float*)d_in[12];
  const float* h0       = (const float*)d_in[13];
  const float* c0       = (const float*)d_in[14];
  float* out = (float*)d_out;

  float* ws = (float*)d_ws;
  float* pre_f = ws;                               // [T][512]
  float* pre_b = pre_f + (size_t)T_LEN * G4;       // [T][512]
  float* hcat  = pre_b + (size_t)T_LEN * G4;       // [T][256]
  float* feats = hcat + (size_t)T_LEN * 2 * HH;    // [T][23]
  unsigned char* bptr = (unsigned char*)(feats + (size_t)T_LEN * KT);
  unsigned char* maps = bptr + (size_t)T_LEN * KT;
  int* btags = (int*)(maps + 256 * KT);
  int* misc  = btags + 256;

  k_pre<<<512, 512, 0, stream>>>(sentence, embed, Wih_f, bih_f, bhh_f,
                                 Wih_b, bih_b, bhh_b, pre_f, pre_b);
  k_lstm<<<2, 512, 0, stream>>>(Whh_f, Whh_b, h0, c0, pre_f, pre_b, hcat);
  k_feats<<<256, 256, 0, stream>>>(hcat, Wout, bout, feats);
  k_vit_fwd<<<1, 64, 0, stream>>>(feats, trans, bptr, out, misc);
  k_compose<<<256, 64, 0, stream>>>(bptr, maps);
  k_backscan<<<1, 64, 0, stream>>>(maps, misc, btags);
  k_backeval<<<256, 64, 0, stream>>>(bptr, btags, out);
}

// Round 3
// 9357.364 us; speedup vs baseline: 1.0647x; 1.0647x over previous
//
#include <hip/hip_runtime.h>

#define T_LEN 8192
#define HH 128
#define G4 512
#define E_DIM 50
#define KT 23
#define START_T 21
#define STOP_T 22
#define NEGV -10000.0f

__device__ __forceinline__ float rl(float v, int lane) {
  return __int_as_float(__builtin_amdgcn_readlane(__float_as_int(v), lane));
}

// quad_perm broadcast of quad-lane P (VALU DPP, not LDS pipe)
template <int CTRL>
__device__ __forceinline__ float quadbcast(float x) {
  return __int_as_float(
      __builtin_amdgcn_mov_dpp(__float_as_int(x), CTRL, 0xF, 0xF, true));
}

// ---------------------------------------------------------------------------
// K1: pre[t][j] = Wih[row(j)] . x_t + bih + bhh   (row permuted: r=((j&3)<<7)|(j>>2))
// ---------------------------------------------------------------------------
__global__ __launch_bounds__(512) void k_pre(
    const int* __restrict__ sentence, const float* __restrict__ embed,
    const float* __restrict__ Wih_f, const float* __restrict__ bih_f, const float* __restrict__ bhh_f,
    const float* __restrict__ Wih_b, const float* __restrict__ bih_b, const float* __restrict__ bhh_b,
    float* __restrict__ pre_f, float* __restrict__ pre_b)
{
  const int dir = blockIdx.x >> 8;
  const int t0 = (blockIdx.x & 255) * 32;
  const float* __restrict__ Wih = dir ? Wih_b : Wih_f;
  const float* __restrict__ bi  = dir ? bih_b : bih_f;
  const float* __restrict__ bh  = dir ? bhh_b : bhh_f;
  float* __restrict__ pre = dir ? pre_b : pre_f;
  const int j = threadIdx.x;
  const int r = ((j & 3) << 7) | (j >> 2);
  float w[E_DIM];
  {
    const float2* w2 = (const float2*)(Wih + r * E_DIM);
#pragma unroll
    for (int q = 0; q < 25; ++q) { float2 v = w2[q]; w[2*q] = v.x; w[2*q+1] = v.y; }
  }
  const float bias = bi[r] + bh[r];
  __shared__ float xs[32][E_DIM];
  __shared__ int sidx[32];
  if (j < 32) sidx[j] = sentence[t0 + j];
  __syncthreads();
  for (int i = j; i < 32 * E_DIM; i += 512) {
    int tl = i / E_DIM;
    int e = i - tl * E_DIM;
    xs[tl][e] = embed[sidx[tl] * E_DIM + e];
  }
  __syncthreads();
  for (int tl = 0; tl < 32; ++tl) {
    float a0 = bias, a1 = 0.f;
#pragma unroll
    for (int e = 0; e < E_DIM; e += 2) {
      a0 += w[e]     * xs[tl][e];
      a1 += w[e + 1] * xs[tl][e + 1];
    }
    pre[(t0 + tl) * G4 + j] = a0 + a1;
  }
}

// ---------------------------------------------------------------------------
// K2: serial LSTM, 1 CU/direction. K-SPLIT design (R3):
//  Phase 1: wave wi computes partial dots over k-slice [16wi,16wi+16).
//   h slice lives in wi's OWN quads -> 16 v_readlane -> SGPR operand FMAs.
//   Lane l owns rows {64m+l}: partial writes are coalesced ds_write_b32.
//  Phase 2 (after ONE barrier): thread j reduces 8 partials for row
//   r2=((j&3)<<7)|(j>>2) (+8g bank swizzle -> 2-way = free), activation,
//   DPP quad_perm broadcasts (VALU) for i,f,g,o, c/h update (quad-replicated).
//  Double-buffered partials -> exactly 1 barrier per step. No LDS h broadcast.
// ---------------------------------------------------------------------------
__global__ __launch_bounds__(512, 2) void k_lstm(
    const float* __restrict__ Whh_f, const float* __restrict__ Whh_b,
    const float* __restrict__ h0, const float* __restrict__ c0,
    const float* __restrict__ pre_f, const float* __restrict__ pre_b,
    float* __restrict__ hcat)
{
  const int dir = blockIdx.x;
  const float* __restrict__ Whh = dir ? Whh_b : Whh_f;
  const float* __restrict__ pre = dir ? pre_b : pre_f;
  const int tid = threadIdx.x;
  const int wi = tid >> 6;      // wave id: k-slice [16wi, 16wi+16)
  const int l  = tid & 63;      // lane
  const int g  = tid & 3;       // gate (0=i,1=f,2=g,3=o) for phase 2
  const int d  = tid >> 2;      // hidden dim for phase 2
  const int r2 = (g << 7) | d;  // gate-row for phase 2

  // FMA-phase weights: w[m*16+kk] = Whh[(64m+l)][16wi+kk]
  float w[128];
#pragma unroll
  for (int m = 0; m < 8; ++m) {
    const float4* w4 = (const float4*)(Whh + (64 * m + l) * 128 + 16 * wi);
#pragma unroll
    for (int q = 0; q < 4; ++q) {
      float4 v = w4[q];
      w[m*16 + 4*q + 0] = v.x; w[m*16 + 4*q + 1] = v.y;
      w[m*16 + 4*q + 2] = v.z; w[m*16 + 4*q + 3] = v.w;
    }
  }

  __shared__ float part[2][8 * 544];   // [buf][wi*544 + row + 8*(row>>7... via m>>1)]

  float c  = c0[dir * HH + d];
  float hq = h0[dir * HH + d];         // h[d], replicated across the quad
  float pcur = pre[(dir ? (T_LEN - 1) : 0) * G4 + tid];

  for (int s = 0; s < T_LEN; ++s) {
    const int t  = dir ? (T_LEN - 1 - s) : s;
    const int sn = (s + 1 < T_LEN) ? (s + 1) : s;
    const int tn = dir ? (T_LEN - 1 - sn) : sn;
    const float pnext = pre[tn * G4 + tid];

    // ---- phase 1: partial dot over my k-slice, h via readlane->SGPR ----
    float acc[8];
#pragma unroll
    for (int m = 0; m < 8; ++m) acc[m] = 0.f;
#pragma unroll
    for (int kk = 0; kk < 16; ++kk) {
      const float hs = rl(hq, 4 * kk);   // quad kk of this wave holds h[16wi+kk]
#pragma unroll
      for (int m = 0; m < 8; ++m) acc[m] += w[m * 16 + kk] * hs;
    }
    {
      float* pb = &part[s & 1][wi * 544 + l];
#pragma unroll
      for (int m = 0; m < 8; ++m) pb[m * 64 + (m >> 1) * 8] = acc[m];  // coalesced
    }
    __syncthreads();

    // ---- phase 2: reduce, activation, c/h update ----
    const float* rb = &part[s & 1][r2 + g * 8];   // +8g: banks (d+8g)%32 -> 2-way
    float sum = rb[0];
#pragma unroll
    for (int wi2 = 1; wi2 < 8; ++wi2) sum += rb[wi2 * 544];
    const float a = sum + pcur;
    pcur = pnext;

    const float sc = (g == 2) ? 2.0f : 1.0f;
    const float ev = __expf(-sc * a);
    const float sg = 1.0f / (1.0f + ev);
    const float act = (g == 2) ? (2.0f * sg - 1.0f) : sg;
    const float iv  = quadbcast<0x00>(act);
    const float fv  = quadbcast<0x55>(act);
    const float gv  = quadbcast<0xAA>(act);
    const float ovv = quadbcast<0xFF>(act);
    c = fv * c + iv * gv;
    const float e2 = __expf(-2.0f * c);
    const float th = 2.0f / (1.0f + e2) - 1.0f;
    hq = ovv * th;                       // replicated in quad; readlaned next step
    if (g == 0) hcat[t * (2 * HH) + dir * HH + d] = hq;
    // no second barrier: double-buffered partials
  }
}

// ---------------------------------------------------------------------------
// K3: feats[t][k] = W_out[k] . hcat[t] + b_out[k]
// ---------------------------------------------------------------------------
__global__ __launch_bounds__(256) void k_feats(
    const float* __restrict__ hcat, const float* __restrict__ Wout,
    const float* __restrict__ bout, float* __restrict__ feats)
{
  const int t0 = blockIdx.x * 32;
  __shared__ float hsh[32 * 257];
  __shared__ float wsh[KT * 256];
  __shared__ float bsh[KT];
  const int tid = threadIdx.x;
  for (int i = tid; i < 32 * 256; i += 256) {
    int tl = i >> 8, dd = i & 255;
    hsh[tl * 257 + dd] = hcat[(t0 + tl) * 256 + dd];
  }
  for (int i = tid; i < KT * 256; i += 256) wsh[i] = Wout[i];
  if (tid < KT) bsh[tid] = bout[tid];
  __syncthreads();
  for (int idx = tid; idx < 32 * KT; idx += 256) {
    int tl = idx & 31, k = idx >> 5;
    float a0 = bsh[k], a1 = 0.f, a2 = 0.f, a3 = 0.f;
#pragma unroll 8
    for (int dd = 0; dd < 256; dd += 4) {
      a0 += hsh[tl * 257 + dd + 0] * wsh[k * 256 + dd + 0];
      a1 += hsh[tl * 257 + dd + 1] * wsh[k * 256 + dd + 1];
      a2 += hsh[tl * 257 + dd + 2] * wsh[k * 256 + dd + 2];
      a3 += hsh[tl * 257 + dd + 3] * wsh[k * 256 + dd + 3];
    }
    feats[(t0 + tl) * KT + k] = ((a0 + a1) + (a2 + a3));
  }
}

// ---------------------------------------------------------------------------
// K4: sequential Viterbi forward — MINIMAL serial body. Per step: store fv
// (off-chain), 23x(readlane+add) feeding a max3 tree, +feat. All backpointer
// work moved to the parallel k_bptr (bitwise-identical candidates).
// ---------------------------------------------------------------------------
__global__ __launch_bounds__(64) void k_vit_fwd(
    const float* __restrict__ feats, const float* __restrict__ trans,
    float* __restrict__ fvstore, float* __restrict__ out, int* __restrict__ misc)
{
  const int j = threadIdx.x;
  float trow[KT];
#pragma unroll
  for (int i = 0; i < KT; ++i)
    trow[i] = (j < KT) ? ((j == START_T || i == STOP_T) ? NEGV : trans[j * KT + i]) : NEGV;
  float fvn = (j == START_T) ? 0.0f : NEGV;
  float pf[8];
#pragma unroll
  for (int q = 0; q < 8; ++q) pf[q] = (j < KT) ? feats[q * KT + j] : 0.0f;

#define MAX3(a,b,cc) fmaxf(fmaxf((a),(b)),(cc))
#define CAND(i) (rl(fvn, (i)) + trow[(i)])

  for (int tb = 0; tb < T_LEN; tb += 8) {
#pragma unroll
    for (int q = 0; q < 8; ++q) {
      const int t = tb + q;
      if (j < KT) fvstore[t * 24 + j] = fvn;      // state BEFORE step t (off-chain)
      float m0 = MAX3(CAND(0),  CAND(1),  CAND(2));
      float m1 = MAX3(CAND(3),  CAND(4),  CAND(5));
      float m2 = MAX3(CAND(6),  CAND(7),  CAND(8));
      float m3 = MAX3(CAND(9),  CAND(10), CAND(11));
      float m4 = MAX3(CAND(12), CAND(13), CAND(14));
      float m5 = MAX3(CAND(15), CAND(16), CAND(17));
      float m6 = MAX3(CAND(18), CAND(19), CAND(20));
      float m7 = fmaxf(CAND(21), CAND(22));
      float n0 = MAX3(m0, m1, m2);
      float n1 = MAX3(m3, m4, m5);
      float n2 = fmaxf(m6, m7);
      const float best = MAX3(n0, n1, n2);        // exact max: order-independent
      fvn = best + pf[q];
      const int tpf = t + 8;
      pf[q] = (j < KT && tpf < T_LEN) ? feats[tpf * KT + j] : 0.0f;
    }
  }
  // terminal: fv + trans_c[STOP]; first-max argmax via tie-aware butterfly
  const float trS = (j < KT) ? ((j == STOP_T) ? NEGV : trans[STOP_T * KT + j]) : 0.0f;
  float term = (j < KT) ? (fvn + trS) : -3.0e38f;
  int idx = (j < KT) ? j : 63;
#pragma unroll
  for (int off = 16; off >= 1; off >>= 1) {
    float ovl = __shfl_xor(term, off);
    int oi = __shfl_xor(idx, off);
    if (ovl > term || (ovl == term && oi < idx)) { term = ovl; idx = oi; }
  }
  if (j == 0) { out[0] = term; misc[0] = idx; }
}

// ---------------------------------------------------------------------------
// K4b: parallel backpointers from stored fv. cand = fv[i]+trow[j][i] — same
// two operands as k_vit => bitwise-identical sums; strict-> linear scan =
// first-max, identical to jnp.argmax.
// ---------------------------------------------------------------------------
__global__ __launch_bounds__(256) void k_bptr(
    const float* __restrict__ fvstore, const float* __restrict__ trans,
    unsigned char* __restrict__ bptr)
{
  const int t0 = blockIdx.x * 32;
  __shared__ float fv[32 * 24];
  __shared__ float trc[KT * KT];
  const int tid = threadIdx.x;
  for (int i = tid; i < 32 * 24; i += 256) fv[i] = fvstore[t0 * 24 + i];
  for (int i = tid; i < KT * KT; i += 256) {
    int jj = i / KT, ii = i - jj * KT;
    trc[i] = (jj == START_T || ii == STOP_T) ? NEGV : trans[i];
  }
  __syncthreads();
  for (int p = tid; p < 32 * KT; p += 256) {
    int tl = p / KT, jj = p - tl * KT;
    const float* fvr = fv + tl * 24;
    const float* tr = trc + jj * KT;
    float best = fvr[0] + tr[0]; int bi = 0;
#pragma unroll
    for (int i = 1; i < KT; ++i) {
      float v = fvr[i] + tr[i];
      if (v > best) { best = v; bi = i; }
    }
    bptr[(t0 + tl) * KT + jj] = (unsigned char)bi;
  }
}

// ---------------------------------------------------------------------------
// K5: compose 32-step backpointer maps per chunk (parallel).
// ---------------------------------------------------------------------------
__global__ __launch_bounds__(64) void k_compose(
    const unsigned char* __restrict__ bptr, unsigned char* __restrict__ maps)
{
  const int c = blockIdx.x;
  const int lo = c * 32;
  __shared__ unsigned char rows[32 * 24];
  const int tid = threadIdx.x;
  for (int i = tid; i < 32 * KT; i += 64) {
    int tl = i / KT, e = i - tl * KT;
    rows[tl * 24 + e] = bptr[(lo + tl) * KT + e];
  }
  __syncthreads();
  if (tid < KT) {
    int x = tid;
    for (int tl = 31; tl >= 0; --tl) x = rows[tl * 24 + x];
    maps[c * KT + tid] = (unsigned char)x;
  }
}

// K6: sequential scan over 256 chunk maps.
__global__ __launch_bounds__(64) void k_backscan(
    const unsigned char* __restrict__ maps, const int* __restrict__ misc,
    int* __restrict__ btags)
{
  __shared__ unsigned char msh[256 * KT];
  const int tid = threadIdx.x;
  for (int i = tid; i < 256 * KT; i += 64) msh[i] = maps[i];
  __syncthreads();
  if (tid == 0) {
    int e = misc[0];
    for (int c = 255; c >= 0; --c) { btags[c] = e; e = msh[c * KT + e]; }
  }
}

// K7: evaluate interior path per chunk (parallel), write tags as floats.
__global__ __launch_bounds__(64) void k_backeval(
    const unsigned char* __restrict__ bptr, const int* __restrict__ btags,
    float* __restrict__ out)
{
  const int c = blockIdx.x;
  const int lo = c * 32;
  __shared__ unsigned char rows[32 * 24];
  __shared__ int tags[32];
  const int tid = threadIdx.x;
  for (int i = tid; i < 32 * KT; i += 64) {
    int tl = i / KT, e = i - tl * KT;
    rows[tl * 24 + e] = bptr[(lo + tl) * KT + e];
  }
  __syncthreads();
  if (tid == 0) {
    int tg = btags[c];
    tags[31] = tg;
    for (int tl = 31; tl >= 1; --tl) { tg = rows[tl * 24 + tg]; tags[tl - 1] = tg; }
  }
  __syncthreads();
  if (tid < 32) out[1 + lo + tid] = (float)tags[tid];
}

// ---------------------------------------------------------------------------
extern "C" void kernel_launch(void* const* d_in, const int* in_sizes, int n_in,
                              void* d_out, int out_size, void* d_ws, size_t ws_size,
                              hipStream_t stream) {
  const int*   sentence = (const int*)d_in[0];
  const float* embed    = (const float*)d_in[1];
  const float* Wih_f    = (const float*)d_in[2];
  const float* Whh_f    = (const float*)d_in[3];
  const float* bih_f    = (const float*)d_in[4];
  const float* bhh_f    = (const float*)d_in[5];
  const float* Wih_b    = (const float*)d_in[6];
  const float* bih_b    = (const float*)d_in[7];
  const float* Whh_b    = (const float*)d_in[7];
  const float* bih_b2   = (const float*)d_in[8];
  (void)bih_b; (void)bih_b2;
  // correct unpack (keep dict order):
  const float* wih_b  = (const float*)d_in[6];
  const float* whh_b  = (const float*)d_in[7];
  const float* bihb   = (const float*)d_in[8];
  const float* bhhb   = (const float*)d_in[9];
  const float* Wout   = (const float*)d_in[10];
  const float* bout   = (const float*)d_in[11];
  const float* trans  = (const float*)d_in[12];
  const float* h0     = (const float*)d_in[13];
  const float* c0     = (const float*)d_in[14];
  float* out = (float*)d_out;

  float* ws = (float*)d_ws;
  float* pre_f = ws;                               // [T][512]
  float* pre_b = pre_f + (size_t)T_LEN * G4;       // [T][512]
  float* hcat  = pre_b + (size_t)T_LEN * G4;       // [T][256]
  float* feats = hcat + (size_t)T_LEN * 2 * HH;    // [T][23]
  unsigned char* bptr = (unsigned char*)(feats + (size_t)T_LEN * KT);
  unsigned char* maps = bptr + (size_t)T_LEN * KT;
  int* btags = (int*)(maps + 256 * KT);
  int* misc  = btags + 256;
  float* fvstore = pre_f;                          // reuse: pre dead after k_lstm

  k_pre<<<512, 512, 0, stream>>>(sentence, embed, Wih_f, bih_f, bhh_f,
                                 wih_b, bihb, bhhb, pre_f, pre_b);
  k_lstm<<<2, 512, 0, stream>>>(Whh_f, whh_b, h0, c0, pre_f, pre_b, hcat);
  k_feats<<<256, 256, 0, stream>>>(hcat, Wout, bout, feats);
  k_vit_fwd<<<1, 64, 0, stream>>>(feats, trans, fvstore, out, misc);
  k_bptr<<<256, 256, 0, stream>>>(fvstore, trans, bptr);
  k_compose<<<256, 64, 0, stream>>>(bptr, maps);
  k_backscan<<<1, 64, 0, stream>>>(maps, misc, btags);
  k_backeval<<<256, 64, 0, stream>>>(bptr, btags, out);
}

// Round 4
// 9328.432 us; speedup vs baseline: 1.0680x; 1.0031x over previous
//
#include <hip/hip_runtime.h>

#define T_LEN 8192
#define HH 128
#define G4 512
#define E_DIM 50
#define KT 23
#define START_T 21
#define STOP_T 22
#define NEGV -10000.0f

__device__ __forceinline__ float rl(float v, int lane) {
  return __int_as_float(__builtin_amdgcn_readlane(__float_as_int(v), lane));
}

template <int CTRL>
__device__ __forceinline__ float quadbcast(float x) {
  return __int_as_float(
      __builtin_amdgcn_mov_dpp(__float_as_int(x), CTRL, 0xF, 0xF, true));
}

// Raw workgroup barrier WITHOUT the vmcnt(0) drain __syncthreads() imposes:
// only LDS (lgkmcnt) is drained; global loads/stores stay in flight.
// 0xC07F = vmcnt(63) expcnt(7) lgkmcnt(0) on gfx9 encoding.
#define RAW_SYNC()                                  \
  do {                                              \
    __builtin_amdgcn_sched_barrier(0);              \
    __builtin_amdgcn_s_waitcnt(0xC07F);             \
    __builtin_amdgcn_s_barrier();                   \
    __builtin_amdgcn_sched_barrier(0);              \
  } while (0)

// ---------------------------------------------------------------------------
// K1: pre[t][j] = Wih[row(j)] . x_t + bih + bhh   (row permuted: r=((j&3)<<7)|(j>>2))
// ---------------------------------------------------------------------------
__global__ __launch_bounds__(512) void k_pre(
    const int* __restrict__ sentence, const float* __restrict__ embed,
    const float* __restrict__ Wih_f, const float* __restrict__ bih_f, const float* __restrict__ bhh_f,
    const float* __restrict__ Wih_b, const float* __restrict__ bih_b, const float* __restrict__ bhh_b,
    float* __restrict__ pre_f, float* __restrict__ pre_b)
{
  const int dir = blockIdx.x >> 8;
  const int t0 = (blockIdx.x & 255) * 32;
  const float* __restrict__ Wih = dir ? Wih_b : Wih_f;
  const float* __restrict__ bi  = dir ? bih_b : bih_f;
  const float* __restrict__ bh  = dir ? bhh_b : bhh_f;
  float* __restrict__ pre = dir ? pre_b : pre_f;
  const int j = threadIdx.x;
  const int r = ((j & 3) << 7) | (j >> 2);
  float w[E_DIM];
  {
    const float2* w2 = (const float2*)(Wih + r * E_DIM);
#pragma unroll
    for (int q = 0; q < 25; ++q) { float2 v = w2[q]; w[2*q] = v.x; w[2*q+1] = v.y; }
  }
  const float bias = bi[r] + bh[r];
  __shared__ float xs[32][E_DIM];
  __shared__ int sidx[32];
  if (j < 32) sidx[j] = sentence[t0 + j];
  __syncthreads();
  for (int i = j; i < 32 * E_DIM; i += 512) {
    int tl = i / E_DIM;
    int e = i - tl * E_DIM;
    xs[tl][e] = embed[sidx[tl] * E_DIM + e];
  }
  __syncthreads();
  for (int tl = 0; tl < 32; ++tl) {
    float a0 = bias, a1 = 0.f;
#pragma unroll
    for (int e = 0; e < E_DIM; e += 2) {
      a0 += w[e]     * xs[tl][e];
      a1 += w[e + 1] * xs[tl][e + 1];
    }
    pre[(t0 + tl) * G4 + j] = a0 + a1;
  }
}

// ---------------------------------------------------------------------------
// K2: serial LSTM, 1 CU/direction, K-split (R3 structure) + RAW_SYNC barrier
// (no vmcnt drain) + depth-2 pre prefetch + tree-sum of partials.
// ---------------------------------------------------------------------------
__global__ __launch_bounds__(512, 2) void k_lstm(
    const float* __restrict__ Whh_f, const float* __restrict__ Whh_b,
    const float* __restrict__ h0, const float* __restrict__ c0,
    const float* __restrict__ pre_f, const float* __restrict__ pre_b,
    float* __restrict__ hcat)
{
  const int dir = blockIdx.x;
  const float* __restrict__ Whh = dir ? Whh_b : Whh_f;
  const float* __restrict__ pre = dir ? pre_b : pre_f;
  const int tid = threadIdx.x;
  const int wi = tid >> 6;      // wave id: k-slice [16wi, 16wi+16)
  const int l  = tid & 63;
  const int g  = tid & 3;       // gate (0=i,1=f,2=g,3=o)
  const int d  = tid >> 2;      // hidden dim
  const int r2 = (g << 7) | d;  // gate-row for phase 2

  float w[128];                 // w[m*16+kk] = Whh[(64m+l)][16wi+kk]
#pragma unroll
  for (int m = 0; m < 8; ++m) {
    const float4* w4 = (const float4*)(Whh + (64 * m + l) * 128 + 16 * wi);
#pragma unroll
    for (int q = 0; q < 4; ++q) {
      float4 v = w4[q];
      w[m*16 + 4*q + 0] = v.x; w[m*16 + 4*q + 1] = v.y;
      w[m*16 + 4*q + 2] = v.z; w[m*16 + 4*q + 3] = v.w;
    }
  }

  __shared__ float part[2][8 * 544];

  float c  = c0[dir * HH + d];
  float hq = h0[dir * HH + d];
  float pcur = pre[(dir ? (T_LEN - 1) : 0) * G4 + tid];
  float pn1  = pre[(dir ? (T_LEN - 2) : 1) * G4 + tid];

  for (int s = 0; s < T_LEN; ++s) {
    const int t  = dir ? (T_LEN - 1 - s) : s;
    const int s2 = (s + 2 < T_LEN) ? (s + 2) : (T_LEN - 1);
    const int t2 = dir ? (T_LEN - 1 - s2) : s2;
    const float pn2 = pre[t2 * G4 + tid];    // depth-2 prefetch, never drained

    // ---- phase 1: partial dot over my k-slice, h via readlane->SGPR ----
    float acc[8];
#pragma unroll
    for (int m = 0; m < 8; ++m) acc[m] = 0.f;
#pragma unroll
    for (int kk = 0; kk < 16; ++kk) {
      const float hs = rl(hq, 4 * kk);
#pragma unroll
      for (int m = 0; m < 8; ++m) acc[m] += w[m * 16 + kk] * hs;
    }
    {
      float* pb = &part[s & 1][wi * 544 + l];
#pragma unroll
      for (int m = 0; m < 8; ++m) pb[m * 64 + (m >> 1) * 8] = acc[m];
    }
    RAW_SYNC();                               // LDS-only drain

    // ---- phase 2: tree-reduce 8 partials, activation, c/h update ----
    const float* rb = &part[s & 1][r2 + g * 8];   // 2-way banks = free
    float r0 = rb[0 * 544], r1 = rb[1 * 544], r2v = rb[2 * 544], r3 = rb[3 * 544];
    float r4 = rb[4 * 544], r5 = rb[5 * 544], r6 = rb[6 * 544], r7 = rb[7 * 544];
    const float sum = ((r0 + r1) + (r2v + r3)) + ((r4 + r5) + (r6 + r7));
    const float a = sum + pcur;
    pcur = pn1; pn1 = pn2;

    const float sc = (g == 2) ? 2.0f : 1.0f;
    const float ev = __expf(-sc * a);
    const float sg = 1.0f / (1.0f + ev);
    const float act = (g == 2) ? (2.0f * sg - 1.0f) : sg;
    const float iv  = quadbcast<0x00>(act);
    const float fv  = quadbcast<0x55>(act);
    const float gv  = quadbcast<0xAA>(act);
    const float ovv = quadbcast<0xFF>(act);
    c = fv * c + iv * gv;
    const float e2 = __expf(-2.0f * c);
    const float th = 2.0f / (1.0f + e2) - 1.0f;
    hq = ovv * th;
    if (g == 0) hcat[t * (2 * HH) + dir * HH + d] = hq;
    // no second barrier: double-buffered partials
  }
}

// ---------------------------------------------------------------------------
// K3: feats[t][k] = W_out[k] . hcat[t] + b_out[k]
// ---------------------------------------------------------------------------
__global__ __launch_bounds__(256) void k_feats(
    const float* __restrict__ hcat, const float* __restrict__ Wout,
    const float* __restrict__ bout, float* __restrict__ feats)
{
  const int t0 = blockIdx.x * 32;
  __shared__ float hsh[32 * 257];
  __shared__ float wsh[KT * 256];
  __shared__ float bsh[KT];
  const int tid = threadIdx.x;
  for (int i = tid; i < 32 * 256; i += 256) {
    int tl = i >> 8, dd = i & 255;
    hsh[tl * 257 + dd] = hcat[(t0 + tl) * 256 + dd];
  }
  for (int i = tid; i < KT * 256; i += 256) wsh[i] = Wout[i];
  if (tid < KT) bsh[tid] = bout[tid];
  __syncthreads();
  for (int idx = tid; idx < 32 * KT; idx += 256) {
    int tl = idx & 31, k = idx >> 5;
    float a0 = bsh[k], a1 = 0.f, a2 = 0.f, a3 = 0.f;
#pragma unroll 8
    for (int dd = 0; dd < 256; dd += 4) {
      a0 += hsh[tl * 257 + dd + 0] * wsh[k * 256 + dd + 0];
      a1 += hsh[tl * 257 + dd + 1] * wsh[k * 256 + dd + 1];
      a2 += hsh[tl * 257 + dd + 2] * wsh[k * 256 + dd + 2];
      a3 += hsh[tl * 257 + dd + 3] * wsh[k * 256 + dd + 3];
    }
    feats[(t0 + tl) * KT + k] = ((a0 + a1) + (a2 + a3));
  }
}

// ---------------------------------------------------------------------------
// K4: sequential Viterbi forward — minimal serial body. fv stored (stride 64,
// all lanes, no exec toggle) for the parallel k_bptr.
// ---------------------------------------------------------------------------
__global__ __launch_bounds__(64) void k_vit_fwd(
    const float* __restrict__ feats, const float* __restrict__ trans,
    float* __restrict__ fvstore, float* __restrict__ out, int* __restrict__ misc)
{
  const int j = threadIdx.x;
  float trow[KT];
#pragma unroll
  for (int i = 0; i < KT; ++i)
    trow[i] = (j < KT) ? ((j == START_T || i == STOP_T) ? NEGV : trans[j * KT + i]) : NEGV;
  float fvn = (j == START_T) ? 0.0f : NEGV;
  float pf[8];
#pragma unroll
  for (int q = 0; q < 8; ++q) pf[q] = (j < KT) ? feats[q * KT + j] : 0.0f;

#define MAX3(a,b,cc) fmaxf(fmaxf((a),(b)),(cc))
#define CAND(i) (rl(fvn, (i)) + trow[(i)])

  for (int tb = 0; tb < T_LEN; tb += 8) {
#pragma unroll
    for (int q = 0; q < 8; ++q) {
      const int t = tb + q;
      fvstore[t * 64 + j] = fvn;                  // off-chain, all lanes
      float m0 = MAX3(CAND(0),  CAND(1),  CAND(2));
      float m1 = MAX3(CAND(3),  CAND(4),  CAND(5));
      float m2 = MAX3(CAND(6),  CAND(7),  CAND(8));
      float m3 = MAX3(CAND(9),  CAND(10), CAND(11));
      float m4 = MAX3(CAND(12), CAND(13), CAND(14));
      float m5 = MAX3(CAND(15), CAND(16), CAND(17));
      float m6 = MAX3(CAND(18), CAND(19), CAND(20));
      float m7 = fmaxf(CAND(21), CAND(22));
      float n0 = MAX3(m0, m1, m2);
      float n1 = MAX3(m3, m4, m5);
      float n2 = fmaxf(m6, m7);
      const float best = MAX3(n0, n1, n2);        // exact max: order-free
      fvn = best + pf[q];
      const int tpf = t + 8;
      pf[q] = (j < KT && tpf < T_LEN) ? feats[tpf * KT + j] : 0.0f;
    }
  }
  const float trS = (j < KT) ? ((j == STOP_T) ? NEGV : trans[STOP_T * KT + j]) : 0.0f;
  float term = (j < KT) ? (fvn + trS) : -3.0e38f;
  int idx = (j < KT) ? j : 63;
#pragma unroll
  for (int off = 16; off >= 1; off >>= 1) {
    float ovl = __shfl_xor(term, off);
    int oi = __shfl_xor(idx, off);
    if (ovl > term || (ovl == term && oi < idx)) { term = ovl; idx = oi; }
  }
  if (j == 0) { out[0] = term; misc[0] = idx; }
}

// ---------------------------------------------------------------------------
// K4b: parallel backpointers from stored fv (bitwise-identical candidates,
// strict-> first-max == jnp.argmax).
// ---------------------------------------------------------------------------
__global__ __launch_bounds__(256) void k_bptr(
    const float* __restrict__ fvstore, const float* __restrict__ trans,
    unsigned char* __restrict__ bptr)
{
  const int t0 = blockIdx.x * 32;
  __shared__ float fv[32 * 24];
  __shared__ float trc[KT * KT];
  const int tid = threadIdx.x;
  for (int i = tid; i < 32 * 24; i += 256) {
    int tl = i / 24, e = i - tl * 24;
    fv[i] = fvstore[(t0 + tl) * 64 + e];
  }
  for (int i = tid; i < KT * KT; i += 256) {
    int jj = i / KT, ii = i - jj * KT;
    trc[i] = (jj == START_T || ii == STOP_T) ? NEGV : trans[i];
  }
  __syncthreads();
  for (int p = tid; p < 32 * KT; p += 256) {
    int tl = p / KT, jj = p - tl * KT;
    const float* fvr = fv + tl * 24;
    const float* tr = trc + jj * KT;
    float best = fvr[0] + tr[0]; int bi = 0;
#pragma unroll
    for (int i = 1; i < KT; ++i) {
      float v = fvr[i] + tr[i];
      if (v > best) { best = v; bi = i; }
    }
    bptr[(t0 + tl) * KT + jj] = (unsigned char)bi;
  }
}

// ---------------------------------------------------------------------------
// K5: compose 32-step backpointer maps per chunk (parallel).
// ---------------------------------------------------------------------------
__global__ __launch_bounds__(64) void k_compose(
    const unsigned char* __restrict__ bptr, unsigned char* __restrict__ maps)
{
  const int c = blockIdx.x;
  const int lo = c * 32;
  __shared__ unsigned char rows[32 * 24];
  const int tid = threadIdx.x;
  for (int i = tid; i < 32 * KT; i += 64) {
    int tl = i / KT, e = i - tl * KT;
    rows[tl * 24 + e] = bptr[(lo + tl) * KT + e];
  }
  __syncthreads();
  if (tid < KT) {
    int x = tid;
    for (int tl = 31; tl >= 0; --tl) x = rows[tl * 24 + x];
    maps[c * KT + tid] = (unsigned char)x;
  }
}

// K6: sequential scan over 256 chunk maps.
__global__ __launch_bounds__(64) void k_backscan(
    const unsigned char* __restrict__ maps, const int* __restrict__ misc,
    int* __restrict__ btags)
{
  __shared__ unsigned char msh[256 * KT];
  const int tid = threadIdx.x;
  for (int i = tid; i < 256 * KT; i += 64) msh[i] = maps[i];
  __syncthreads();
  if (tid == 0) {
    int e = misc[0];
    for (int c = 255; c >= 0; --c) { btags[c] = e; e = msh[c * KT + e]; }
  }
}

// K7: evaluate interior path per chunk (parallel), write tags as floats.
__global__ __launch_bounds__(64) void k_backeval(
    const unsigned char* __restrict__ bptr, const int* __restrict__ btags,
    float* __restrict__ out)
{
  const int c = blockIdx.x;
  const int lo = c * 32;
  __shared__ unsigned char rows[32 * 24];
  __shared__ int tags[32];
  const int tid = threadIdx.x;
  for (int i = tid; i < 32 * KT; i += 64) {
    int tl = i / KT, e = i - tl * KT;
    rows[tl * 24 + e] = bptr[(lo + tl) * KT + e];
  }
  __syncthreads();
  if (tid == 0) {
    int tg = btags[c];
    tags[31] = tg;
    for (int tl = 31; tl >= 1; --tl) { tg = rows[tl * 24 + tg]; tags[tl - 1] = tg; }
  }
  __syncthreads();
  if (tid < 32) out[1 + lo + tid] = (float)tags[tid];
}

// ---------------------------------------------------------------------------
extern "C" void kernel_launch(void* const* d_in, const int* in_sizes, int n_in,
                              void* d_out, int out_size, void* d_ws, size_t ws_size,
                              hipStream_t stream) {
  const int*   sentence = (const int*)d_in[0];
  const float* embed    = (const float*)d_in[1];
  const float* Wih_f    = (const float*)d_in[2];
  const float* Whh_f    = (const float*)d_in[3];
  const float* bih_f    = (const float*)d_in[4];
  const float* bhh_f    = (const float*)d_in[5];
  const float* Wih_b    = (const float*)d_in[6];
  const float* Whh_b    = (const float*)d_in[7];
  const float* bih_b    = (const float*)d_in[8];
  const float* bhh_b    = (const float*)d_in[9];
  const float* Wout     = (const float*)d_in[10];
  const float* bout     = (const float*)d_in[11];
  const float* trans    = (const float*)d_in[12];
  const float* h0       = (const float*)d_in[13];
  const float* c0       = (const float*)d_in[14];
  float* out = (float*)d_out;

  float* ws = (float*)d_ws;
  float* pre_f = ws;                               // [T][512]
  float* pre_b = pre_f + (size_t)T_LEN * G4;       // [T][512]
  float* hcat  = pre_b + (size_t)T_LEN * G4;       // [T][256]
  float* feats = hcat + (size_t)T_LEN * 2 * HH;    // [T][23]
  unsigned char* bptr = (unsigned char*)(feats + (size_t)T_LEN * KT);
  unsigned char* maps = bptr + (size_t)T_LEN * KT;
  int* btags = (int*)(maps + 256 * KT);
  int* misc  = btags + 256;
  float* fvstore = pre_f;                          // [T][64], pre dead after k_lstm

  k_pre<<<512, 512, 0, stream>>>(sentence, embed, Wih_f, bih_f, bhh_f,
                                 Wih_b, bih_b, bhh_b, pre_f, pre_b);
  k_lstm<<<2, 512, 0, stream>>>(Whh_f, Whh_b, h0, c0, pre_f, pre_b, hcat);
  k_feats<<<256, 256, 0, stream>>>(hcat, Wout, bout, feats);
  k_vit_fwd<<<1, 64, 0, stream>>>(feats, trans, fvstore, out, misc);
  k_bptr<<<256, 256, 0, stream>>>(fvstore, trans, bptr);
  k_compose<<<256, 64, 0, stream>>>(bptr, maps);
  k_backscan<<<1, 64, 0, stream>>>(maps, misc, btags);
  k_backeval<<<256, 64, 0, stream>>>(bptr, btags, out);
}

// Round 5
// 9060.913 us; speedup vs baseline: 1.0995x; 1.0295x over previous
//
#include <hip/hip_runtime.h>

#define T_LEN 8192
#define HH 128
#define G4 512
#define E_DIM 50
#define KT 23
#define START_T 21
#define STOP_T 22
#define NEGV -10000.0f

__device__ __forceinline__ float rl(float v, int lane) {
  return __int_as_float(__builtin_amdgcn_readlane(__float_as_int(v), lane));
}

// Packed fp32 FMA: acc.xy += w.xy * h.xy  (one VOP3P instr = 2 MACs).
// "v" constraints force ARCH VGPR homes for w/acc -> no v_accvgpr_read tax.
__device__ __forceinline__ void pkfma(float2& acc, const float2 w, const float2 h) {
  asm volatile("v_pk_fma_f32 %0, %1, %2, %0" : "+v"(acc) : "v"(w), "v"(h));
}

// ---------------------------------------------------------------------------
// K1: pre[t][j] = Wih[row(j)] . x_t + bih + bhh   (row permuted: r=((j&3)<<7)|(j>>2))
// ---------------------------------------------------------------------------
__global__ __launch_bounds__(512) void k_pre(
    const int* __restrict__ sentence, const float* __restrict__ embed,
    const float* __restrict__ Wih_f, const float* __restrict__ bih_f, const float* __restrict__ bhh_f,
    const float* __restrict__ Wih_b, const float* __restrict__ bih_b, const float* __restrict__ bhh_b,
    float* __restrict__ pre_f, float* __restrict__ pre_b)
{
  const int dir = blockIdx.x >> 8;
  const int t0 = (blockIdx.x & 255) * 32;
  const float* __restrict__ Wih = dir ? Wih_b : Wih_f;
  const float* __restrict__ bi  = dir ? bih_b : bih_f;
  const float* __restrict__ bh  = dir ? bhh_b : bhh_f;
  float* __restrict__ pre = dir ? pre_b : pre_f;
  const int j = threadIdx.x;
  const int r = ((j & 3) << 7) | (j >> 2);
  float w[E_DIM];
  {
    const float2* w2 = (const float2*)(Wih + r * E_DIM);
#pragma unroll
    for (int q = 0; q < 25; ++q) { float2 v = w2[q]; w[2*q] = v.x; w[2*q+1] = v.y; }
  }
  const float bias = bi[r] + bh[r];
  __shared__ float xs[32][E_DIM];
  __shared__ int sidx[32];
  if (j < 32) sidx[j] = sentence[t0 + j];
  __syncthreads();
  for (int i = j; i < 32 * E_DIM; i += 512) {
    int tl = i / E_DIM;
    int e = i - tl * E_DIM;
    xs[tl][e] = embed[sidx[tl] * E_DIM + e];
  }
  __syncthreads();
  for (int tl = 0; tl < 32; ++tl) {
    float a0 = bias, a1 = 0.f;
#pragma unroll
    for (int e = 0; e < E_DIM; e += 2) {
      a0 += w[e]     * xs[tl][e];
      a1 += w[e + 1] * xs[tl][e + 1];
    }
    pre[(t0 + tl) * G4 + j] = a0 + a1;
  }
}

// ---------------------------------------------------------------------------
// K2: serial LSTM, 1 CU/direction. R1 structure (fastest so far) + packed
// fp32 FMA via inline asm: 64 v_pk_fma_f32 instead of 128 v_fmac + 128
// v_accvgpr_read (VGPR_Count=76-80 in R1-R4 proved w[] was AGPR-homed).
// Thread j = gate-row ((j&3)<<7)|(j>>2); quad = i,f,g,o of one hidden dim.
// h broadcast: 32 uniform ds_read_b128/wave; 1 __syncthreads/step.
// ---------------------------------------------------------------------------
__global__ __launch_bounds__(512, 2) void k_lstm(
    const float* __restrict__ Whh_f, const float* __restrict__ Whh_b,
    const float* __restrict__ h0, const float* __restrict__ c0,
    const float* __restrict__ pre_f, const float* __restrict__ pre_b,
    float* __restrict__ hcat)
{
  const int dir = blockIdx.x;
  const float* __restrict__ Whh = dir ? Whh_b : Whh_f;
  const float* __restrict__ pre = dir ? pre_b : pre_f;
  const int j = threadIdx.x;
  const int g = j & 3;        // 0=i,1=f,2=g,3=o
  const int d = j >> 2;       // hidden dim
  const int r = (g << 7) | d; // Whh row
  float2 w[64];
  {
    const float2* wsrc = (const float2*)(Whh + r * 128);
#pragma unroll
    for (int q = 0; q < 64; ++q) w[q] = wsrc[q];
  }
  __shared__ float hbuf[2][HH];
  float c = c0[dir * HH + d];
  if (g == 0) hbuf[0][d] = h0[dir * HH + d];
  __syncthreads();
  float pcur = pre[(dir ? (T_LEN - 1) : 0) * G4 + j];
  float pn1  = pre[(dir ? (T_LEN - 2) : 1) * G4 + j];

  for (int s = 0; s < T_LEN; ++s) {
    const int t  = dir ? (T_LEN - 1 - s) : s;
    const int s2 = (s + 2 < T_LEN) ? (s + 2) : (T_LEN - 1);
    const int t2 = dir ? (T_LEN - 1 - s2) : s2;
    const float pn2 = pre[t2 * G4 + j];      // depth-2 prefetch

    const float4* h4 = (const float4*)hbuf[s & 1];
    float2 a0 = {0.f, 0.f}, a1 = {0.f, 0.f}, a2 = {0.f, 0.f}, a3 = {0.f, 0.f};
#pragma unroll
    for (int q = 0; q < 32; q += 2) {
      float4 hva = h4[q];
      float4 hvb = h4[q + 1];
      pkfma(a0, w[2*q + 0], make_float2(hva.x, hva.y));
      pkfma(a1, w[2*q + 1], make_float2(hva.z, hva.w));
      pkfma(a2, w[2*q + 2], make_float2(hvb.x, hvb.y));
      pkfma(a3, w[2*q + 3], make_float2(hvb.z, hvb.w));
    }
    const float sum = ((a0.x + a0.y) + (a1.x + a1.y)) +
                      ((a2.x + a2.y) + (a3.x + a3.y));
    const float acc = sum + pcur;
    pcur = pn1; pn1 = pn2;

    const float sc = (g == 2) ? 2.0f : 1.0f;
    const float ev = __expf(-sc * acc);
    const float sg = 1.0f / (1.0f + ev);
    const float act = (g == 2) ? (2.0f * sg - 1.0f) : sg;
    const float iv  = __shfl(act, 0, 4);
    const float fv  = __shfl(act, 1, 4);
    const float gv  = __shfl(act, 2, 4);
    const float ovv = __shfl(act, 3, 4);
    c = fv * c + iv * gv;
    const float e2 = __expf(-2.0f * c);
    const float th = 2.0f / (1.0f + e2) - 1.0f;
    const float h = ovv * th;
    if (g == 0) {
      hbuf[(s + 1) & 1][d] = h;              // double-buffer: 1 barrier/step
      hcat[t * (2 * HH) + dir * HH + d] = h;
    }
    __syncthreads();
  }
}

// ---------------------------------------------------------------------------
// K3: feats32[t][k] = W_out[k] . hcat[t] + b_out[k]   (stride-32 layout so
// k_vit_fwd can load unconditionally from all 64 lanes)
// ---------------------------------------------------------------------------
__global__ __launch_bounds__(256) void k_feats(
    const float* __restrict__ hcat, const float* __restrict__ Wout,
    const float* __restrict__ bout, float* __restrict__ feats32)
{
  const int t0 = blockIdx.x * 32;
  __shared__ float hsh[32 * 257];
  __shared__ float wsh[KT * 256];
  __shared__ float bsh[KT];
  const int tid = threadIdx.x;
  for (int i = tid; i < 32 * 256; i += 256) {
    int tl = i >> 8, dd = i & 255;
    hsh[tl * 257 + dd] = hcat[(t0 + tl) * 256 + dd];
  }
  for (int i = tid; i < KT * 256; i += 256) wsh[i] = Wout[i];
  if (tid < KT) bsh[tid] = bout[tid];
  __syncthreads();
  for (int idx = tid; idx < 32 * KT; idx += 256) {
    int tl = idx & 31, k = idx >> 5;
    float a0 = bsh[k], a1 = 0.f, a2 = 0.f, a3 = 0.f;
#pragma unroll 8
    for (int dd = 0; dd < 256; dd += 4) {
      a0 += hsh[tl * 257 + dd + 0] * wsh[k * 256 + dd + 0];
      a1 += hsh[tl * 257 + dd + 1] * wsh[k * 256 + dd + 1];
      a2 += hsh[tl * 257 + dd + 2] * wsh[k * 256 + dd + 2];
      a3 += hsh[tl * 257 + dd + 3] * wsh[k * 256 + dd + 3];
    }
    feats32[(t0 + tl) * 32 + k] = ((a0 + a1) + (a2 + a3));
  }
}

// ---------------------------------------------------------------------------
// K4: sequential Viterbi forward — branch-free loop body (no exec toggles):
// all 64 lanes load/store unconditionally (stride-32 feats, clamped index).
// ---------------------------------------------------------------------------
__global__ __launch_bounds__(64) void k_vit_fwd(
    const float* __restrict__ feats32, const float* __restrict__ trans,
    float* __restrict__ fvstore, float* __restrict__ out, int* __restrict__ misc)
{
  const int j = threadIdx.x;
  const int j32 = j & 31;
  float trow[KT];
#pragma unroll
  for (int i = 0; i < KT; ++i)
    trow[i] = (j < KT) ? ((j == START_T || i == STOP_T) ? NEGV : trans[j * KT + i]) : NEGV;
  float fvn = (j == START_T) ? 0.0f : NEGV;
  float pf[8];
#pragma unroll
  for (int q = 0; q < 8; ++q) pf[q] = feats32[q * 32 + j32];

#define MAX3(a,b,cc) fmaxf(fmaxf((a),(b)),(cc))
#define CAND(i) (rl(fvn, (i)) + trow[(i)])

  for (int tb = 0; tb < T_LEN; tb += 8) {
#pragma unroll
    for (int q = 0; q < 8; ++q) {
      const int t = tb + q;
      fvstore[t * 64 + j] = fvn;                  // off-chain, all lanes
      float m0 = MAX3(CAND(0),  CAND(1),  CAND(2));
      float m1 = MAX3(CAND(3),  CAND(4),  CAND(5));
      float m2 = MAX3(CAND(6),  CAND(7),  CAND(8));
      float m3 = MAX3(CAND(9),  CAND(10), CAND(11));
      float m4 = MAX3(CAND(12), CAND(13), CAND(14));
      float m5 = MAX3(CAND(15), CAND(16), CAND(17));
      float m6 = MAX3(CAND(18), CAND(19), CAND(20));
      float m7 = fmaxf(CAND(21), CAND(22));
      float n0 = MAX3(m0, m1, m2);
      float n1 = MAX3(m3, m4, m5);
      float n2 = fmaxf(m6, m7);
      const float best = MAX3(n0, n1, n2);        // exact max: order-free
      fvn = best + pf[q];
      const int tpf = t + 8;
      const int tc = (tpf < T_LEN) ? tpf : (T_LEN - 1);
      pf[q] = feats32[tc * 32 + j32];             // unconditional
    }
  }
  const float trS = (j < KT) ? ((j == STOP_T) ? NEGV : trans[STOP_T * KT + j]) : 0.0f;
  float term = (j < KT) ? (fvn + trS) : -3.0e38f;
  int idx = (j < KT) ? j : 63;
#pragma unroll
  for (int off = 16; off >= 1; off >>= 1) {
    float ovl = __shfl_xor(term, off);
    int oi = __shfl_xor(idx, off);
    if (ovl > term || (ovl == term && oi < idx)) { term = ovl; idx = oi; }
  }
  if (j == 0) { out[0] = term; misc[0] = idx; }
}

// ---------------------------------------------------------------------------
// K4b: parallel backpointers from stored fv (bitwise-identical candidates,
// strict-> first-max == jnp.argmax).
// ---------------------------------------------------------------------------
__global__ __launch_bounds__(256) void k_bptr(
    const float* __restrict__ fvstore, const float* __restrict__ trans,
    unsigned char* __restrict__ bptr)
{
  const int t0 = blockIdx.x * 32;
  __shared__ float fv[32 * 24];
  __shared__ float trc[KT * KT];
  const int tid = threadIdx.x;
  for (int i = tid; i < 32 * 24; i += 256) {
    int tl = i / 24, e = i - tl * 24;
    fv[i] = fvstore[(t0 + tl) * 64 + e];
  }
  for (int i = tid; i < KT * KT; i += 256) {
    int jj = i / KT, ii = i - jj * KT;
    trc[i] = (jj == START_T || ii == STOP_T) ? NEGV : trans[i];
  }
  __syncthreads();
  for (int p = tid; p < 32 * KT; p += 256) {
    int tl = p / KT, jj = p - tl * KT;
    const float* fvr = fv + tl * 24;
    const float* tr = trc + jj * KT;
    float best = fvr[0] + tr[0]; int bi = 0;
#pragma unroll
    for (int i = 1; i < KT; ++i) {
      float v = fvr[i] + tr[i];
      if (v > best) { best = v; bi = i; }
    }
    bptr[(t0 + tl) * KT + jj] = (unsigned char)bi;
  }
}

// ---------------------------------------------------------------------------
// K5: compose 32-step backpointer maps per chunk (parallel).
// ---------------------------------------------------------------------------
__global__ __launch_bounds__(64) void k_compose(
    const unsigned char* __restrict__ bptr, unsigned char* __restrict__ maps)
{
  const int c = blockIdx.x;
  const int lo = c * 32;
  __shared__ unsigned char rows[32 * 24];
  const int tid = threadIdx.x;
  for (int i = tid; i < 32 * KT; i += 64) {
    int tl = i / KT, e = i - tl * KT;
    rows[tl * 24 + e] = bptr[(lo + tl) * KT + e];
  }
  __syncthreads();
  if (tid < KT) {
    int x = tid;
    for (int tl = 31; tl >= 0; --tl) x = rows[tl * 24 + x];
    maps[c * KT + tid] = (unsigned char)x;
  }
}

// K6: sequential scan over 256 chunk maps.
__global__ __launch_bounds__(64) void k_backscan(
    const unsigned char* __restrict__ maps, const int* __restrict__ misc,
    int* __restrict__ btags)
{
  __shared__ unsigned char msh[256 * KT];
  const int tid = threadIdx.x;
  for (int i = tid; i < 256 * KT; i += 64) msh[i] = maps[i];
  __syncthreads();
  if (tid == 0) {
    int e = misc[0];
    for (int c = 255; c >= 0; --c) { btags[c] = e; e = msh[c * KT + e]; }
  }
}

// K7: evaluate interior path per chunk (parallel), write tags as floats.
__global__ __launch_bounds__(64) void k_backeval(
    const unsigned char* __restrict__ bptr, const int* __restrict__ btags,
    float* __restrict__ out)
{
  const int c = blockIdx.x;
  const int lo = c * 32;
  __shared__ unsigned char rows[32 * 24];
  __shared__ int tags[32];
  const int tid = threadIdx.x;
  for (int i = tid; i < 32 * KT; i += 64) {
    int tl = i / KT, e = i - tl * KT;
    rows[tl * 24 + e] = bptr[(lo + tl) * KT + e];
  }
  __syncthreads();
  if (tid == 0) {
    int tg = btags[c];
    tags[31] = tg;
    for (int tl = 31; tl >= 1; --tl) { tg = rows[tl * 24 + tg]; tags[tl - 1] = tg; }
  }
  __syncthreads();
  if (tid < 32) out[1 + lo + tid] = (float)tags[tid];
}

// ---------------------------------------------------------------------------
extern "C" void kernel_launch(void* const* d_in, const int* in_sizes, int n_in,
                              void* d_out, int out_size, void* d_ws, size_t ws_size,
                              hipStream_t stream) {
  const int*   sentence = (const int*)d_in[0];
  const float* embed    = (const float*)d_in[1];
  const float* Wih_f    = (const float*)d_in[2];
  const float* Whh_f    = (const float*)d_in[3];
  const float* bih_f    = (const float*)d_in[4];
  const float* bhh_f    = (const float*)d_in[5];
  const float* Wih_b    = (const float*)d_in[6];
  const float* Whh_b    = (const float*)d_in[7];
  const float* bih_b    = (const float*)d_in[8];
  const float* bhh_b    = (const float*)d_in[9];
  const float* Wout     = (const float*)d_in[10];
  const float* bout     = (const float*)d_in[11];
  const float* trans    = (const float*)d_in[12];
  const float* h0       = (const float*)d_in[13];
  const float* c0       = (const float*)d_in[14];
  float* out = (float*)d_out;

  float* ws = (float*)d_ws;
  float* pre_f = ws;                               // [T][512]
  float* pre_b = pre_f + (size_t)T_LEN * G4;       // [T][512]
  float* hcat  = pre_b + (size_t)T_LEN * G4;       // [T][256]
  float* feats32 = hcat + (size_t)T_LEN * 2 * HH;  // [T][32]
  unsigned char* bptr = (unsigned char*)(feats32 + (size_t)T_LEN * 32);
  unsigned char* maps = bptr + (size_t)T_LEN * KT;
  int* btags = (int*)(maps + 256 * KT);
  int* misc  = btags + 256;
  float* fvstore = pre_f;                          // [T][64], pre dead after k_lstm

  k_pre<<<512, 512, 0, stream>>>(sentence, embed, Wih_f, bih_f, bhh_f,
                                 Wih_b, bih_b, bhh_b, pre_f, pre_b);
  k_lstm<<<2, 512, 0, stream>>>(Whh_f, Whh_b, h0, c0, pre_f, pre_b, hcat);
  k_feats<<<256, 256, 0, stream>>>(hcat, Wout, bout, feats32);
  k_vit_fwd<<<1, 64, 0, stream>>>(feats32, trans, fvstore, out, misc);
  k_bptr<<<256, 256, 0, stream>>>(fvstore, trans, bptr);
  k_compose<<<256, 64, 0, stream>>>(bptr, maps);
  k_backscan<<<1, 64, 0, stream>>>(maps, misc, btags);
  k_backeval<<<256, 64, 0, stream>>>(bptr, btags, out);
}